// Round 4
// baseline (587.755 us; speedup 1.0000x reference)
//
#include <hip/hip_runtime.h>

// Problem constants: image (C,H,W) fp32, flow (2,H,W) fp32.
constexpr int C  = 32;
constexpr int H  = 1024;
constexpr int W  = 2048;
constexpr int HW = H * W;

constexpr int TW = 64;              // tile width  (pixels); wave = one pixel row
constexpr int TH = 32;              // tile height (pixels)
constexpr int NPX = (TW * TH) / 256;// 8 pixels per thread

constexpr int CPB = 8;              // channels per block (amortize precompute)
constexpr int ZB  = C / CPB;        // 4 z-groups
constexpr int GX  = W / TW;         // 32
constexpr int GY  = H / TH;         // 32
constexpr int NWG = GX * GY * ZB;   // 4096 blocks

// Direct-gather version: no LDS, no barriers. The N(0,1) flow keeps the 2x2
// footprints within ~±4 px of the pixel, so gathers are L1/L2-local. All
// latency is hidden by per-thread MLP (32 independent loads per channel) and
// VGPR-limited occupancy instead of a serialized stage->barrier->read chain.
__global__ __launch_bounds__(256) void warp_kernel(
    const float* __restrict__ image,
    const float* __restrict__ flow,
    float* __restrict__ out)
{
    // ---- bijective XCD chunking: XCD x owns a contiguous chunk of tiles ----
    const int flat = blockIdx.x;                       // 0..4095
    const int nid  = (flat & 7) * (NWG / 8) + (flat >> 3);
    const int bx   = nid & (GX - 1);
    const int by   = (nid / GX) & (GY - 1);
    const int bz   = nid / (GX * GY);

    const int tid = threadIdx.x;
    const int tx0 = bx * TW;
    const int ty0 = by * TH;
    const int c0  = bz * CPB;

    // ---- per-pixel precompute (channel-invariant) ----
    const int tx  = tid & (TW - 1);
    const int tyq = tid >> 6;                 // 0..3 (wave id = pixel row within quad)
    const int xpx = tx0 + tx;
    const int po0 = (ty0 + tyq) * W + xpx;    // pixel flat offset, row stride 4*W per i

    float w00[NPX], w10[NPX], w01[NPX], w11[NPX];
    int a00[NPX], du[NPX], dv[NPX];

    #pragma unroll
    for (int i = 0; i < NPX; ++i) {
        const int po  = po0 + i * 4 * W;
        const int ypx = ty0 + tyq + 4 * i;
        const float u = (float)xpx + flow[po];
        const float v = (float)ypx + flow[HW + po];
        const float u0f = floorf(u);
        const float v0f = floorf(v);
        const float wu = u - u0f;
        const float wv = v - v0f;
        const int u0 = (int)u0f;
        const int v0 = (int)v0f;

        const bool vu0 = (u0 >= 0) & (u0 <= W - 1);
        const bool vu1 = (u0 + 1 >= 0) & (u0 + 1 <= W - 1);
        const bool vv0 = (v0 >= 0) & (v0 <= H - 1);
        const bool vv1 = (v0 + 1 >= 0) & (v0 + 1 <= H - 1);

        // Fold validity into weights: w * where(valid,g,0) == (valid?w:0)*g_clamped.
        const float a = (1.0f - wu) * (1.0f - wv);
        const float b = wu * (1.0f - wv);
        const float c = (1.0f - wu) * wv;
        const float d = wu * wv;
        w00[i] = (vv0 & vu0) ? a : 0.0f;
        w10[i] = (vv0 & vu1) ? b : 0.0f;
        w01[i] = (vv1 & vu0) ? c : 0.0f;
        w11[i] = (vv1 & vu1) ? d : 0.0f;

        // Clamped corner addresses; all four derived addresses are in-bounds
        // by construction (invalid corners have zero weight anyway).
        const int u0c = min(max(u0, 0), W - 1);
        const int u1c = min(max(u0 + 1, 0), W - 1);
        const int v0c = min(max(v0, 0), H - 1);
        const int v1c = min(max(v0 + 1, 0), H - 1);
        a00[i] = v0c * W + u0c;
        du[i]  = u1c - u0c;            // 0 or 1
        dv[i]  = (v1c - v0c) * W;      // 0 or W
    }

    // ---- channel loop: pure gather, no synchronization ----
    for (int cc = 0; cc < CPB; ++cc) {
        const int c = c0 + cc;
        const float* __restrict__ imgc = image + (size_t)c * HW;
        float* __restrict__ outc = out + (size_t)c * HW;

        #pragma unroll
        for (int i = 0; i < NPX; ++i) {
            const int base = a00[i];
            const float g00 = imgc[base];
            const float g10 = imgc[base + du[i]];
            const float g01 = imgc[base + dv[i]];
            const float g11 = imgc[base + du[i] + dv[i]];
            const float r = w00[i] * g00 + w10[i] * g10
                          + w01[i] * g01 + w11[i] * g11;
            // Output is never re-read: keep it from evicting image lines.
            __builtin_nontemporal_store(r, &outc[po0 + i * 4 * W]);
        }
    }
}

extern "C" void kernel_launch(void* const* d_in, const int* in_sizes, int n_in,
                              void* d_out, int out_size, void* d_ws, size_t ws_size,
                              hipStream_t stream) {
    const float* image = (const float*)d_in[0];
    const float* flow  = (const float*)d_in[1];
    float* out = (float*)d_out;

    warp_kernel<<<dim3(NWG), 256, 0, stream>>>(image, flow, out);
}

// Round 5
// 459.021 us; speedup vs baseline: 1.2805x; 1.2805x over previous
//
#include <hip/hip_runtime.h>
#include <stdint.h>

// Problem constants: image (C,H,W) fp32, flow (2,H,W) fp32.
constexpr int C  = 32;
constexpr int H  = 1024;
constexpr int W  = 2048;
constexpr int HW = H * W;

constexpr int TW = 64;               // tile width  (pixels)
constexpr int TH = 32;               // tile height (pixels)
constexpr int MC = 4;                // col margin each side (multiple of 4!)
constexpr int MR = 4;                // row margin each side
constexpr int SC = TW + 2 * MC;      // 72 staged cols
constexpr int SR = TH + 2 * MR;      // 40 staged rows
constexpr int SLOTS = SR * (SC / 4); // 720 float4 staging slots
constexpr int CALLS = 3;             // global_load_lds calls per thread
constexpr int SLOT_PAD = 256 * CALLS;// 768 slots incl. pad: every call is full-wave
constexpr int NPX = (TW * TH) / 256; // 8 pixels per thread

constexpr int CPB = 8;               // channels per block
constexpr int ZB  = C / CPB;         // 4 z-groups
constexpr int GX  = W / TW;          // 32
constexpr int GY  = H / TH;          // 32
constexpr int NWG = GX * GY * ZB;    // 4096 blocks
constexpr int NB  = 3;               // triple buffer -> prefetch depth 2

typedef const __attribute__((address_space(1))) uint32_t* gp1_t;
typedef __attribute__((address_space(3))) uint32_t* lp3_t;

// Round-5 design: LDS staging via global_load_lds (no VGPR roundtrip, layout is
// already linear in slot index) + triple-buffered prefetch depth 2 so each
// HBM staging load (~900 cyc) is covered by TWO channel-compute periods.
// Counted s_waitcnt vmcnt(8) — never drain — keeps next-channel staging loads
// and output stores in flight across the single per-channel barrier.
__global__ __launch_bounds__(256) void warp_kernel(
    const float* __restrict__ image,
    const float* __restrict__ flow,
    float* __restrict__ out)
{
    __shared__ float lsbuf[NB][SLOT_PAD * 4];   // 3 x 12288 B = 36864 B

    // ---- bijective XCD chunking ----
    const int flat = blockIdx.x;                       // 0..4095
    const int nid  = (flat & 7) * (NWG / 8) + (flat >> 3);
    const int bx   = nid & (GX - 1);
    const int by   = (nid / GX) & (GY - 1);
    const int bz   = nid / (GX * GY);

    const int tid = threadIdx.x;
    const int tx0 = bx * TW;
    const int ty0 = by * TH;
    const int c0  = bz * CPB;

    // ---- staging source offsets (channel-invariant) ----
    // Slot s stages image[srow][scol..scol+3] into LDS floats [4s..4s+4).
    // Source clamped to [0,W-4]: with MC=4 and tx0%4==0 every 16B group is
    // fully in-image or fully OOB; OOB groups stage finite duplicates that
    // are only ever multiplied by folded weight 0.
    int goff[CALLS];
    #pragma unroll
    for (int k = 0; k < CALLS; ++k) {
        const int s    = tid + 256 * k;
        const int r    = s / (SC / 4);
        const int c4   = (s - r * (SC / 4)) * 4;
        const int srow = min(max(ty0 - MR + r, 0), H - 1);
        const int scol = min(max(tx0 - MC + c4, 0), W - 4);
        goff[k] = srow * W + scol;
    }
    const int wavebase = tid & 192;    // wave-uniform slot base (wave id * 64)

    auto stage = [&](int c, int b) {
        const float* __restrict__ src = image + (size_t)c * HW;
        #pragma unroll
        for (int k = 0; k < CALLS; ++k) {
            const float* gp = src + goff[k];
            // dest: wave-uniform base; HW adds lane*16 -> linear slot layout
            lp3_t lp = (lp3_t)(void*)((char*)&lsbuf[b][0]
                                      + (size_t)(256 * k + wavebase) * 16);
            __builtin_amdgcn_global_load_lds((gp1_t)(const void*)gp, lp, 16, 0, 0);
        }
    };

    // ---- issue first staging immediately: HBM latency hides under precompute
    stage(c0 + 0, 0);

    // ---- per-pixel precompute (channel-invariant): weights + LDS addr ----
    const int tx  = tid & (TW - 1);
    const int tyq = tid >> 6;                 // 0..3
    const int xpx = tx0 + tx;
    const int po0 = (ty0 + tyq) * W + xpx;    // pixel flat offset, stride 4*W per i

    float w00[NPX], w10[NPX], w01[NPX], w11[NPX];
    int addr0[NPX];
    unsigned fmask = 0;

    #pragma unroll
    for (int i = 0; i < NPX; ++i) {
        const int po  = po0 + i * 4 * W;
        const int ypx = ty0 + tyq + 4 * i;
        const float u = (float)xpx + flow[po];
        const float v = (float)ypx + flow[HW + po];
        const float u0f = floorf(u);
        const float v0f = floorf(v);
        const float wu = u - u0f;
        const float wv = v - v0f;
        const int u0 = (int)u0f;
        const int v0 = (int)v0f;

        const bool vu0 = (u0 >= 0) & (u0 <= W - 1);
        const bool vu1 = (u0 + 1 >= 0) & (u0 + 1 <= W - 1);
        const bool vv0 = (v0 >= 0) & (v0 <= H - 1);
        const bool vv1 = (v0 + 1 >= 0) & (v0 + 1 <= H - 1);

        // Fold validity into weights: w * where(valid,g,0) == (valid?w:0)*g.
        const float a = (1.0f - wu) * (1.0f - wv);
        const float b = wu * (1.0f - wv);
        const float c = (1.0f - wu) * wv;
        const float d = wu * wv;
        w00[i] = (vv0 & vu0) ? a : 0.0f;
        w10[i] = (vv0 & vu1) ? b : 0.0f;
        w01[i] = (vv1 & vu0) ? c : 0.0f;
        w11[i] = (vv1 & vu1) ? d : 0.0f;

        // Fast path iff the 2x2 footprint lies inside the staged window.
        const bool fast = (u0 >= tx0 - MC) & (u0 <= tx0 + TW + MC - 2) &
                          (v0 >= ty0 - MR) & (v0 <= ty0 + TH + MR - 2);
        fmask |= (fast ? 1u : 0u) << i;
        addr0[i] = (v0 - ty0 + MR) * SC + (u0 - tx0 + MC);
    }

    // ---- second staging in flight before the loop ----
    stage(c0 + 1, 1);

    // ---- channel loop: 1 barrier/channel, counted vmcnt, depth-2 prefetch ----
    // Safety of vmcnt(8): vmcnt retires in issue order; ops newer than the
    // last load of stage(c) are >= 8 stores (+ any fallback loads) + 3 loads
    // of stage(c+1), so <=8 outstanding implies stage(c) has landed, while
    // stage(c+1) (newest 3) stays in flight.
    #pragma unroll
    for (int cc = 0; cc < CPB; ++cc) {
        if (cc == 0) asm volatile("s_waitcnt vmcnt(3)" ::: "memory");
        else         asm volatile("s_waitcnt vmcnt(8)" ::: "memory");
        __builtin_amdgcn_s_barrier();

        const int c = c0 + cc;
        const float* __restrict__ ls   = &lsbuf[cc % NB][0];
        const float* __restrict__ imgc = image + (size_t)c * HW;
        float* __restrict__ outc       = out + (size_t)c * HW;

        #pragma unroll
        for (int i = 0; i < NPX; ++i) {
            const int po = po0 + i * 4 * W;
            float r;
            if ((fmask >> i) & 1u) {
                const int a0 = addr0[i];
                const float g00 = ls[a0];
                const float g10 = ls[a0 + 1];
                const float g01 = ls[a0 + SC];
                const float g11 = ls[a0 + SC + 1];
                r = w00[i] * g00 + w10[i] * g10 + w01[i] * g01 + w11[i] * g11;
            } else {
                // Rare outlier (|flow| beyond margin): global clamped fallback.
                const int ypx = ty0 + tyq + 4 * i;
                const float u = (float)xpx + flow[po];
                const float v = (float)ypx + flow[HW + po];
                const int u0 = (int)floorf(u);
                const int v0 = (int)floorf(v);
                const int u0c = min(max(u0, 0), W - 1);
                const int u1c = min(max(u0 + 1, 0), W - 1);
                const int v0c = min(max(v0, 0), H - 1);
                const int v1c = min(max(v0 + 1, 0), H - 1);
                r = w00[i] * imgc[v0c * W + u0c] + w10[i] * imgc[v0c * W + u1c]
                  + w01[i] * imgc[v1c * W + u0c] + w11[i] * imgc[v1c * W + u1c];
            }
            // Output is never re-read: keep it from evicting image lines.
            __builtin_nontemporal_store(r, &outc[po]);
        }

        // Prefetch 2 channels ahead into buf[(cc+2)%3] == buf[(cc-1)%3]:
        // every wave passed this iteration's barrier, i.e. finished reading it.
        if (cc + 2 < CPB) stage(c + 2, (cc + 2) % NB);
    }
}

extern "C" void kernel_launch(void* const* d_in, const int* in_sizes, int n_in,
                              void* d_out, int out_size, void* d_ws, size_t ws_size,
                              hipStream_t stream) {
    const float* image = (const float*)d_in[0];
    const float* flow  = (const float*)d_in[1];
    float* out = (float*)d_out;

    warp_kernel<<<dim3(NWG), 256, 0, stream>>>(image, flow, out);
}

// Round 7
// 456.999 us; speedup vs baseline: 1.2861x; 1.0044x over previous
//
#include <hip/hip_runtime.h>
#include <stdint.h>

// Problem constants: image (C,H,W) fp32, flow (2,H,W) fp32.
constexpr int C  = 32;
constexpr int H  = 1024;
constexpr int W  = 2048;
constexpr int HW = H * W;

constexpr int TW = 64;               // tile width  (pixels)
constexpr int TH = 32;               // tile height (pixels)
constexpr int MC = 4;                // col margin each side (multiple of 4!)
constexpr int MR = 4;                // row margin each side
constexpr int SC = TW + 2 * MC;      // 72 staged cols
constexpr int SR = TH + 2 * MR;      // 40 staged rows
constexpr int SLOTS = SR * (SC / 4); // 720 float4 staging slots
constexpr int CALLS = 3;             // global_load_lds calls per thread
constexpr int SLOT_PAD = 256 * CALLS;// 768 slots incl. pad: every call is full-wave
constexpr int NPX = (TW * TH) / 256; // 8 pixels per thread

constexpr int CPB = 8;               // channels per block
constexpr int ZB  = C / CPB;         // 4 z-groups
constexpr int GX  = W / TW;          // 32
constexpr int GY  = H / TH;          // 32
constexpr int NWG = GX * GY * ZB;    // 4096 blocks
constexpr int NB  = 3;               // triple buffer -> prefetch depth 2

typedef const __attribute__((address_space(1))) uint32_t* gp1_t;
typedef __attribute__((address_space(3))) uint32_t* lp3_t;

// Round-6 schedule (resubmitted after infra failure): global_load_lds staging,
// triple buffer, EXACT counted vmcnt per iteration = number of VMEM ops
// provably issued after stage(cc)'s last load:
//   pre-loop: s0,s1.  iter cc: [wait][barrier][stage(cc+2)][compute: 8 stores]
//   cc=0: newer(s0) = s1(3)                          -> vmcnt(3)
//   cc=1: newer(s1) = s2(3)+stores0(8)               -> vmcnt(11)
//   cc in 2..CPB-2: stores(cc-2)8 + s(cc+1)3 + stores(cc-1)8 -> vmcnt(19)
//   cc=CPB-1: stores(cc-2)8 + stores(cc-1)8          -> vmcnt(16)
// Steady state waits only on a load issued TWO channels (~800+ cyc) earlier:
// output stores younger than 2 channels are never drained (round-5's vmcnt(8)
// waited on ~400-cycle-old stores every channel = the residual convoy).
// Fallback loads only add ops NEWER than stage(cc) => bounds stay correct.
__global__ __launch_bounds__(256) void warp_kernel(
    const float* __restrict__ image,
    const float* __restrict__ flow,
    float* __restrict__ out)
{
    __shared__ float lsbuf[NB][SLOT_PAD * 4];   // 3 x 12288 B = 36864 B

    // ---- bijective XCD chunking ----
    const int flat = blockIdx.x;                       // 0..4095
    const int nid  = (flat & 7) * (NWG / 8) + (flat >> 3);
    const int bx   = nid & (GX - 1);
    const int by   = (nid / GX) & (GY - 1);
    const int bz   = nid / (GX * GY);

    const int tid = threadIdx.x;
    const int tx0 = bx * TW;
    const int ty0 = by * TH;
    const int c0  = bz * CPB;

    // ---- staging source offsets (channel-invariant) ----
    // Slot s stages image[srow][scol..scol+3] into LDS floats [4s..4s+4).
    // Source clamped to [0,W-4]: with MC=4 and tx0%4==0 every 16B group is
    // fully in-image or fully OOB; OOB groups stage finite duplicates that
    // are only ever multiplied by folded weight 0.
    int goff[CALLS];
    #pragma unroll
    for (int k = 0; k < CALLS; ++k) {
        const int s    = tid + 256 * k;
        const int r    = s / (SC / 4);
        const int c4   = (s - r * (SC / 4)) * 4;
        const int srow = min(max(ty0 - MR + r, 0), H - 1);
        const int scol = min(max(tx0 - MC + c4, 0), W - 4);
        goff[k] = srow * W + scol;
    }
    const int wavebase = tid & 192;    // wave-uniform slot base (wave id * 64)

    auto stage = [&](int c, int b) {
        const float* __restrict__ src = image + (size_t)c * HW;
        #pragma unroll
        for (int k = 0; k < CALLS; ++k) {
            const float* gp = src + goff[k];
            // dest: wave-uniform base; HW adds lane*16 -> linear slot layout
            lp3_t lp = (lp3_t)(void*)((char*)&lsbuf[b][0]
                                      + (size_t)(256 * k + wavebase) * 16);
            __builtin_amdgcn_global_load_lds((gp1_t)(const void*)gp, lp, 16, 0, 0);
        }
    };

    // ---- issue first staging immediately: HBM latency hides under precompute
    stage(c0 + 0, 0);

    // ---- per-pixel precompute (channel-invariant): weights + LDS addr ----
    const int tx  = tid & (TW - 1);
    const int tyq = tid >> 6;                 // 0..3
    const int xpx = tx0 + tx;
    const int po0 = (ty0 + tyq) * W + xpx;    // pixel flat offset, stride 4*W per i

    float w00[NPX], w10[NPX], w01[NPX], w11[NPX];
    int addr0[NPX];
    unsigned fmask = 0;

    #pragma unroll
    for (int i = 0; i < NPX; ++i) {
        const int po  = po0 + i * 4 * W;
        const int ypx = ty0 + tyq + 4 * i;
        const float u = (float)xpx + flow[po];
        const float v = (float)ypx + flow[HW + po];
        const float u0f = floorf(u);
        const float v0f = floorf(v);
        const float wu = u - u0f;
        const float wv = v - v0f;
        const int u0 = (int)u0f;
        const int v0 = (int)v0f;

        const bool vu0 = (u0 >= 0) & (u0 <= W - 1);
        const bool vu1 = (u0 + 1 >= 0) & (u0 + 1 <= W - 1);
        const bool vv0 = (v0 >= 0) & (v0 <= H - 1);
        const bool vv1 = (v0 + 1 >= 0) & (v0 + 1 <= H - 1);

        // Fold validity into weights: w * where(valid,g,0) == (valid?w:0)*g.
        const float a = (1.0f - wu) * (1.0f - wv);
        const float b = wu * (1.0f - wv);
        const float c = (1.0f - wu) * wv;
        const float d = wu * wv;
        w00[i] = (vv0 & vu0) ? a : 0.0f;
        w10[i] = (vv0 & vu1) ? b : 0.0f;
        w01[i] = (vv1 & vu0) ? c : 0.0f;
        w11[i] = (vv1 & vu1) ? d : 0.0f;

        // Fast path iff the 2x2 footprint lies inside the staged window.
        const bool fast = (u0 >= tx0 - MC) & (u0 <= tx0 + TW + MC - 2) &
                          (v0 >= ty0 - MR) & (v0 <= ty0 + TH + MR - 2);
        fmask |= (fast ? 1u : 0u) << i;
        addr0[i] = (v0 - ty0 + MR) * SC + (u0 - tx0 + MC);
    }

    // ---- second staging in flight before the loop ----
    stage(c0 + 1, 1);

    // ---- channel loop: 1 barrier/channel, exact counted vmcnt, depth-2 ----
    #pragma unroll
    for (int cc = 0; cc < CPB; ++cc) {
        if (cc == 0)            asm volatile("s_waitcnt vmcnt(3)"  ::: "memory");
        else if (cc == 1)       asm volatile("s_waitcnt vmcnt(11)" ::: "memory");
        else if (cc == CPB - 1) asm volatile("s_waitcnt vmcnt(16)" ::: "memory");
        else                    asm volatile("s_waitcnt vmcnt(19)" ::: "memory");
        __builtin_amdgcn_s_barrier();

        // Prefetch 2 ahead into buf[(cc+2)%3] == buf[(cc-1)%3]: every wave
        // consumed its buf[cc-1] reads into registers before passing this
        // barrier, so the buffer is free. Issuing BEFORE compute adds ~half a
        // channel of latency cover.
        if (cc + 2 < CPB) stage(c0 + cc + 2, (cc + 2) % NB);

        const int c = c0 + cc;
        const float* __restrict__ ls   = &lsbuf[cc % NB][0];
        const float* __restrict__ imgc = image + (size_t)c * HW;
        float* __restrict__ outc       = out + (size_t)c * HW;

        #pragma unroll
        for (int i = 0; i < NPX; ++i) {
            const int po = po0 + i * 4 * W;
            float r;
            if ((fmask >> i) & 1u) {
                const int a0 = addr0[i];
                const float g00 = ls[a0];
                const float g10 = ls[a0 + 1];
                const float g01 = ls[a0 + SC];
                const float g11 = ls[a0 + SC + 1];
                r = w00[i] * g00 + w10[i] * g10 + w01[i] * g01 + w11[i] * g11;
            } else {
                // Rare outlier (|flow| beyond margin): global clamped fallback.
                const int ypx = ty0 + tyq + 4 * i;
                const float u = (float)xpx + flow[po];
                const float v = (float)ypx + flow[HW + po];
                const int u0 = (int)floorf(u);
                const int v0 = (int)floorf(v);
                const int u0c = min(max(u0, 0), W - 1);
                const int u1c = min(max(u0 + 1, 0), W - 1);
                const int v0c = min(max(v0, 0), H - 1);
                const int v1c = min(max(v0 + 1, 0), H - 1);
                r = w00[i] * imgc[v0c * W + u0c] + w10[i] * imgc[v0c * W + u1c]
                  + w01[i] * imgc[v1c * W + u0c] + w11[i] * imgc[v1c * W + u1c];
            }
            // Output is never re-read: keep it from evicting image lines.
            __builtin_nontemporal_store(r, &outc[po]);
        }
    }
}

extern "C" void kernel_launch(void* const* d_in, const int* in_sizes, int n_in,
                              void* d_out, int out_size, void* d_ws, size_t ws_size,
                              hipStream_t stream) {
    const float* image = (const float*)d_in[0];
    const float* flow  = (const float*)d_in[1];
    float* out = (float*)d_out;

    warp_kernel<<<dim3(NWG), 256, 0, stream>>>(image, flow, out);
}